// Round 11
// baseline (581.190 us; speedup 1.0000x reference)
//
#include <hip/hip_runtime.h>
#include <math.h>

// ================= degree / normalization =================

__global__ void deg_init_kernel(int* __restrict__ deg, int n) {
    int i = blockIdx.x * blockDim.x + threadIdx.x;
    if (i < n) deg[i] = 1;  // self loop
}

__global__ void deg_count_kernel(const int* __restrict__ dst, int E, int* __restrict__ deg) {
    int i = blockIdx.x * blockDim.x + threadIdx.x;
    if (i < E) atomicAdd(&deg[dst[i]], 1);
}

__global__ void dis_kernel(const int* __restrict__ deg, float* __restrict__ dis, int n) {
    int i = blockIdx.x * blockDim.x + threadIdx.x;
    if (i < n) dis[i] = rsqrtf((float)deg[i]);
}

// ================= CSR build: 3-phase parallel exclusive scan (validated round 8) =================

__global__ void scan_partial_kernel(const int* __restrict__ deg, int* __restrict__ bsum, int n) {
    __shared__ int sm[256];
    const int b = blockIdx.x, tid = threadIdx.x;
    const int base = b * 1024 + tid * 4;
    int s = 0;
#pragma unroll
    for (int j = 0; j < 4; ++j) {
        int i = base + j;
        if (i < n) s += deg[i] - 1;
    }
    sm[tid] = s;
    __syncthreads();
    for (int off = 128; off > 0; off >>= 1) {
        if (tid < off) sm[tid] += sm[tid + off];
        __syncthreads();
    }
    if (tid == 0) bsum[b] = sm[0];
}

// single block; nb <= 256 required (n <= 262144)
__global__ void scan_bsum_kernel(int* __restrict__ bsum, int nb) {
    __shared__ int sm[256];
    const int tid = threadIdx.x;
    int v = (tid < nb) ? bsum[tid] : 0;
    sm[tid] = v;
    __syncthreads();
    for (int off = 1; off < 256; off <<= 1) {
        int t = (tid >= off) ? sm[tid - off] : 0;
        __syncthreads();
        sm[tid] += t;
        __syncthreads();
    }
    if (tid < nb) bsum[tid] = sm[tid] - v;  // exclusive
}

__global__ void scan_fill_kernel(const int* __restrict__ deg, const int* __restrict__ bsum,
                                 int* __restrict__ row_start, int* __restrict__ cursor,
                                 int n, int E) {
    __shared__ int sm[256];
    const int b = blockIdx.x, tid = threadIdx.x;
    const int base = b * 1024 + tid * 4;
    int v[4];
    int s = 0;
#pragma unroll
    for (int j = 0; j < 4; ++j) {
        int i = base + j;
        v[j] = (i < n) ? (deg[i] - 1) : 0;
        s += v[j];
    }
    sm[tid] = s;
    __syncthreads();
    for (int off = 1; off < 256; off <<= 1) {
        int t = (tid >= off) ? sm[tid - off] : 0;
        __syncthreads();
        sm[tid] += t;
        __syncthreads();
    }
    int run = bsum[b] + sm[tid] - s;
#pragma unroll
    for (int j = 0; j < 4; ++j) {
        int i = base + j;
        if (i < n) {
            row_start[i] = run;
            cursor[i] = run;
            run += v[j];
        }
    }
    if (b == 0 && tid == 0) row_start[n] = E;  // sum(indeg) == E exactly
}

__global__ void csr_fill_kernel(const int* __restrict__ src, const int* __restrict__ dst,
                                int E, int* __restrict__ cursor, int* __restrict__ csr) {
    int e = blockIdx.x * blockDim.x + threadIdx.x;
    if (e < E) {
        int pos = atomicAdd(&cursor[dst[e]], 1);
        csr[pos] = src[e];
    }
}

// ================= fp32 GEMM: 2 cols/thread, W-pipelined =================
// C[M,NT] = op_in(A[M,KT]) @ W[KT,NT] (+bias) (relu_out) (optionally * dis[row])
// NCT = NT/2 col-threads; rg = tid/NCT handles TMG rows. Block = NCT*RG threads.
// Each ds_read_b128 of A (wave-broadcast, conflict-free) feeds 8 FMAs (2 cols):
// LDS pipe 12cyc vs VALU 16cyc per (row,kchunk) -> FMA-bound.

template<int KT, int NT, int TMG, int RG, bool RELU_IN, bool RELU_OUT, bool BIAS, bool DIS_SCALE>
__global__ __launch_bounds__((NT / 2) * RG) void gemm_kernel(
    const float* __restrict__ A, const float* __restrict__ W,
    const float* __restrict__ bias, const float* __restrict__ dis,
    float* __restrict__ C, int M) {
    constexpr int NCT = NT / 2;
    constexpr int TM  = TMG * RG;
    extern __shared__ float As[];  // TM*KT floats
    const int row0 = blockIdx.x * TM;
    const int tid  = threadIdx.x;
    const int col2 = (tid & (NCT - 1)) * 2;  // first of 2 adjacent cols
    const int rg   = tid / NCT;

    constexpr int TOTAL = TM * KT;
    for (int idx = tid; idx < TOTAL; idx += NCT * RG) {
        int r = idx / KT;
        int k = idx - r * KT;
        int gr = row0 + r;
        float v = (gr < M) ? A[(size_t)gr * KT + k] : 0.0f;
        if (RELU_IN) v = fmaxf(v, 0.0f);
        As[idx] = v;
    }
    __syncthreads();

    float accx[TMG], accy[TMG];
#pragma unroll
    for (int r = 0; r < TMG; ++r) { accx[r] = 0.0f; accy[r] = 0.0f; }

    const float* Ab = As + rg * TMG * KT;
    const float* Wc = W + col2;

    struct W4 { float2 w0, w1, w2, w3; };
    auto ldW = [&](int k) {
        W4 w;
        w.w0 = *(const float2*)(Wc + (size_t)(k + 0) * NT);
        w.w1 = *(const float2*)(Wc + (size_t)(k + 1) * NT);
        w.w2 = *(const float2*)(Wc + (size_t)(k + 2) * NT);
        w.w3 = *(const float2*)(Wc + (size_t)(k + 3) * NT);
        return w;
    };
    auto step = [&](int k, W4 w) {
#pragma unroll
        for (int r = 0; r < TMG; ++r) {
            float4 a = *(const float4*)(Ab + r * KT + k);
            accx[r] += a.x * w.w0.x + a.y * w.w1.x + a.z * w.w2.x + a.w * w.w3.x;
            accy[r] += a.x * w.w0.y + a.y * w.w1.y + a.z * w.w2.y + a.w * w.w3.y;
        }
    };

    // rotated 2-deep pipeline: prefetch next W chunk before current FMAs
    W4 wa = ldW(0), wb;
    int k = 0;
    while (true) {
        if (k + 4 < KT) wb = ldW(k + 4);
        step(k, wa);
        k += 4;
        if (k >= KT) break;
        if (k + 4 < KT) wa = ldW(k + 4);
        step(k, wb);
        k += 4;
        if (k >= KT) break;
    }

    float bx = BIAS ? bias[col2] : 0.0f;
    float by = BIAS ? bias[col2 + 1] : 0.0f;
#pragma unroll
    for (int r = 0; r < TMG; ++r) {
        int gr = row0 + rg * TMG + r;
        if (gr < M) {
            float vx = accx[r], vy = accy[r];
            if (DIS_SCALE) { float dd = dis[gr]; vx *= dd; vy *= dd; }
            vx += bx; vy += by;
            if (RELU_OUT) { vx = fmaxf(vx, 0.0f); vy = fmaxf(vy, 0.0f); }
            *(float2*)(C + (size_t)gr * NT + col2) = make_float2(vx, vy);
        }
    }
}

// ================= CSR gather aggregation (validated round 5) =================
// out[d] = (maybe relu)( dis[d] * (y[d] + sum_{s in N(d)} y[s]) + bias )

template<bool RELU>
__global__ void gather128_kernel(const float* __restrict__ y, const int* __restrict__ row_start,
                                 const int* __restrict__ csr, const float* __restrict__ dis,
                                 const float* __restrict__ bias, float* __restrict__ out, int n) {
    int w = (blockIdx.x * blockDim.x + threadIdx.x) >> 6;
    if (w >= n) return;
    int lane = threadIdx.x & 63;

    float2 acc = ((const float2*)(y + (size_t)w * 128))[lane];  // self loop
    int p  = row_start[w];
    int pe = row_start[w + 1];
    for (; p + 1 < pe; p += 2) {
        int s0 = __builtin_amdgcn_readfirstlane(csr[p]);
        int s1 = __builtin_amdgcn_readfirstlane(csr[p + 1]);
        float2 v0 = ((const float2*)(y + (size_t)s0 * 128))[lane];
        float2 v1 = ((const float2*)(y + (size_t)s1 * 128))[lane];
        acc.x += v0.x + v1.x;
        acc.y += v0.y + v1.y;
    }
    if (p < pe) {
        int s0 = __builtin_amdgcn_readfirstlane(csr[p]);
        float2 v0 = ((const float2*)(y + (size_t)s0 * 128))[lane];
        acc.x += v0.x;
        acc.y += v0.y;
    }
    float dd = dis[w];
    float2 b = ((const float2*)bias)[lane];
    float ox = acc.x * dd + b.x;
    float oy = acc.y * dd + b.y;
    if (RELU) { ox = fmaxf(ox, 0.0f); oy = fmaxf(oy, 0.0f); }
    ((float2*)(out + (size_t)w * 128))[lane] = make_float2(ox, oy);
}

template<bool RELU>
__global__ void gather64_kernel(const float* __restrict__ y, const int* __restrict__ row_start,
                                const int* __restrict__ csr, const float* __restrict__ dis,
                                const float* __restrict__ bias, float* __restrict__ out, int n) {
    int w = (blockIdx.x * blockDim.x + threadIdx.x) >> 6;
    if (w >= n) return;
    int lane = threadIdx.x & 63;

    float acc = y[(size_t)w * 64 + lane];  // self loop
    int p  = row_start[w];
    int pe = row_start[w + 1];
    for (; p + 1 < pe; p += 2) {
        int s0 = __builtin_amdgcn_readfirstlane(csr[p]);
        int s1 = __builtin_amdgcn_readfirstlane(csr[p + 1]);
        float v0 = y[(size_t)s0 * 64 + lane];
        float v1 = y[(size_t)s1 * 64 + lane];
        acc += v0 + v1;
    }
    if (p < pe) {
        int s0 = __builtin_amdgcn_readfirstlane(csr[p]);
        acc += y[(size_t)s0 * 64 + lane];
    }
    float v = acc * dis[w] + bias[lane];
    if (RELU) v = fmaxf(v, 0.0f);
    out[(size_t)w * 64 + lane] = v;
}

// ================= launch =================

extern "C" void kernel_launch(void* const* d_in, const int* in_sizes, int n_in,
                              void* d_out, int out_size, void* d_ws, size_t ws_size,
                              hipStream_t stream) {
    const float* x     = (const float*)d_in[0];  // [n,180]
    const float* fc1_w = (const float*)d_in[1];  // [180,128]
    const float* fc1_b = (const float*)d_in[2];  // [128]
    const float* w1    = (const float*)d_in[3];  // [128,128]
    const float* b1    = (const float*)d_in[4];  // [128]
    const float* w2    = (const float*)d_in[5];  // [128,64]
    const float* b2    = (const float*)d_in[6];  // [64]
    const int*   edges = (const int*)d_in[7];    // [2,E] int32

    const int IN_DIM = 180, HID = 128, OUT_DIM = 64;
    const int n = in_sizes[0] / IN_DIM;          // 50000
    const int E = in_sizes[7] / 2;               // 800000
    const int* src = edges;
    const int* dst = edges + E;

    float* out = (float*)d_out;                  // [n,64]

    char* ws = (char*)d_ws;
    auto align = [](size_t v) { return (v + 255) & ~(size_t)255; };

    size_t off = 0;
    int*   deg       = (int*)(ws + off);  off += align((size_t)n * sizeof(int));
    float* dis       = (float*)(ws + off); off += align((size_t)n * sizeof(float));
    int*   row_start = (int*)(ws + off);  off += align((size_t)(n + 1) * sizeof(int));
    int*   cursor    = (int*)(ws + off);  off += align((size_t)n * sizeof(int));
    int*   bsum      = (int*)(ws + off);  off += align((size_t)256 * sizeof(int));
    int*   csr       = (int*)(ws + off);  off += align((size_t)E * sizeof(int));
    float* bufA      = (float*)(ws + off); off += align((size_t)n * HID * sizeof(float));
    float* bufB      = (float*)(ws + off); off += align((size_t)n * HID * sizeof(float));
    (void)ws_size;

    const int TM = 32;                            // rows per GEMM block (all shapes)
    const int nblk256 = (n + 255) / 256;
    const int eblk256 = (E + 255) / 256;
    const int ggrid = (n + TM - 1) / TM;          // 1563
    const int scan_blocks = (n + 1023) / 1024;    // 49 (<=256 required)

    // degree + normalization
    deg_init_kernel<<<nblk256, 256, 0, stream>>>(deg, n);
    deg_count_kernel<<<eblk256, 256, 0, stream>>>(dst, E, deg);
    dis_kernel<<<nblk256, 256, 0, stream>>>(deg, dis, n);

    // CSR build
    scan_partial_kernel<<<scan_blocks, 256, 0, stream>>>(deg, bsum, n);
    scan_bsum_kernel<<<1, 256, 0, stream>>>(bsum, scan_blocks);
    scan_fill_kernel<<<scan_blocks, 256, 0, stream>>>(deg, bsum, row_start, cursor, n, E);
    csr_fill_kernel<<<eblk256, 256, 0, stream>>>(src, dst, E, cursor, csr);

    // H1 = relu(x @ fc1_w + fc1_b) -> bufA      (64 col-threads, RG=4, TMG=8)
    gemm_kernel<180, 128, 8, 4, false, true, true, false>
        <<<ggrid, 256, TM * 180 * sizeof(float), stream>>>(
            x, fc1_w, fc1_b, nullptr, bufA, n);

    // y1 = dis * (H1 @ w1) -> bufB
    gemm_kernel<128, 128, 8, 4, false, false, false, true>
        <<<ggrid, 256, TM * 128 * sizeof(float), stream>>>(
            bufA, w1, nullptr, dis, bufB, n);

    // H2 = relu(dis[d]*(y1[d] + sum y1[s]) + b1) -> bufA
    gather128_kernel<true><<<(n + 3) / 4, 256, 0, stream>>>(
        bufB, row_start, csr, dis, b1, bufA, n);

    // y2 = dis * (H2 @ w2) -> bufB               (32 col-threads, RG=8, TMG=4)
    gemm_kernel<128, 64, 4, 8, false, false, false, true>
        <<<ggrid, 256, TM * 128 * sizeof(float), stream>>>(
            bufA, w2, nullptr, dis, bufB, n);

    // out = dis[d]*(y2[d] + sum y2[s]) + b2
    gather64_kernel<false><<<(n + 3) / 4, 256, 0, stream>>>(
        bufB, row_start, csr, dis, b2, out, n);
}

// Round 12
// 424.528 us; speedup vs baseline: 1.3690x; 1.3690x over previous
//
#include <hip/hip_runtime.h>
#include <math.h>

// ================= degree / normalization =================

__global__ void deg_init_kernel(int* __restrict__ deg, int n) {
    int i = blockIdx.x * blockDim.x + threadIdx.x;
    if (i < n) deg[i] = 1;  // self loop
}

__global__ void deg_count_kernel(const int* __restrict__ dst, int E, int* __restrict__ deg) {
    int i = blockIdx.x * blockDim.x + threadIdx.x;
    if (i < E) atomicAdd(&deg[dst[i]], 1);
}

__global__ void dis_kernel(const int* __restrict__ deg, float* __restrict__ dis, int n) {
    int i = blockIdx.x * blockDim.x + threadIdx.x;
    if (i < n) dis[i] = rsqrtf((float)deg[i]);
}

// ================= CSR build: 3-phase parallel exclusive scan (validated round 8) =================

__global__ void scan_partial_kernel(const int* __restrict__ deg, int* __restrict__ bsum, int n) {
    __shared__ int sm[256];
    const int b = blockIdx.x, tid = threadIdx.x;
    const int base = b * 1024 + tid * 4;
    int s = 0;
#pragma unroll
    for (int j = 0; j < 4; ++j) {
        int i = base + j;
        if (i < n) s += deg[i] - 1;
    }
    sm[tid] = s;
    __syncthreads();
    for (int off = 128; off > 0; off >>= 1) {
        if (tid < off) sm[tid] += sm[tid + off];
        __syncthreads();
    }
    if (tid == 0) bsum[b] = sm[0];
}

// single block; nb <= 256 required (n <= 262144)
__global__ void scan_bsum_kernel(int* __restrict__ bsum, int nb) {
    __shared__ int sm[256];
    const int tid = threadIdx.x;
    int v = (tid < nb) ? bsum[tid] : 0;
    sm[tid] = v;
    __syncthreads();
    for (int off = 1; off < 256; off <<= 1) {
        int t = (tid >= off) ? sm[tid - off] : 0;
        __syncthreads();
        sm[tid] += t;
        __syncthreads();
    }
    if (tid < nb) bsum[tid] = sm[tid] - v;  // exclusive
}

__global__ void scan_fill_kernel(const int* __restrict__ deg, const int* __restrict__ bsum,
                                 int* __restrict__ row_start, int* __restrict__ cursor,
                                 int n, int E) {
    __shared__ int sm[256];
    const int b = blockIdx.x, tid = threadIdx.x;
    const int base = b * 1024 + tid * 4;
    int v[4];
    int s = 0;
#pragma unroll
    for (int j = 0; j < 4; ++j) {
        int i = base + j;
        v[j] = (i < n) ? (deg[i] - 1) : 0;
        s += v[j];
    }
    sm[tid] = s;
    __syncthreads();
    for (int off = 1; off < 256; off <<= 1) {
        int t = (tid >= off) ? sm[tid - off] : 0;
        __syncthreads();
        sm[tid] += t;
        __syncthreads();
    }
    int run = bsum[b] + sm[tid] - s;
#pragma unroll
    for (int j = 0; j < 4; ++j) {
        int i = base + j;
        if (i < n) {
            row_start[i] = run;
            cursor[i] = run;
            run += v[j];
        }
    }
    if (b == 0 && tid == 0) row_start[n] = E;  // sum(indeg) == E exactly
}

__global__ void csr_fill_kernel(const int* __restrict__ src, const int* __restrict__ dst,
                                int E, int* __restrict__ cursor, int* __restrict__ csr) {
    int e = blockIdx.x * blockDim.x + threadIdx.x;
    if (e < E) {
        int pos = atomicAdd(&cursor[dst[e]], 1);
        csr[pos] = src[e];
    }
}

// ================= fp32 GEMM: 2 cols/thread, un-hoistable K-loop =================
// C[M,NT] = op_in(A[M,KT]) @ W[KT,NT] (+bias) (relu_out) (optionally * dis[row])
// NCT = NT/2 col-threads; rg = tid/NCT handles TMG rows. Block = NCT*RG threads.
// Round-11 lesson: full unroll of the pipelined K-loop hoisted all W loads ->
// 256 VGPR + 340MB scratch spill. Fix: #pragma unroll 1 rotation (one W4 in
// flight) + __launch_bounds__(.,4) VGPR cap 128 so codegen can never spill-cliff.

template<int KT, int NT, int TMG, int RG, bool RELU_IN, bool RELU_OUT, bool BIAS, bool DIS_SCALE>
__global__ __launch_bounds__((NT / 2) * RG, 4) void gemm_kernel(
    const float* __restrict__ A, const float* __restrict__ W,
    const float* __restrict__ bias, const float* __restrict__ dis,
    float* __restrict__ C, int M) {
    constexpr int NCT = NT / 2;
    constexpr int TM  = TMG * RG;
    extern __shared__ float As[];  // TM*KT floats
    const int row0 = blockIdx.x * TM;
    const int tid  = threadIdx.x;
    const int col2 = (tid & (NCT - 1)) * 2;  // first of 2 adjacent cols
    const int rg   = tid / NCT;

    constexpr int TOTAL = TM * KT;
    for (int idx = tid; idx < TOTAL; idx += NCT * RG) {
        int r = idx / KT;
        int k = idx - r * KT;
        int gr = row0 + r;
        float v = (gr < M) ? A[(size_t)gr * KT + k] : 0.0f;
        if (RELU_IN) v = fmaxf(v, 0.0f);
        As[idx] = v;
    }
    __syncthreads();

    float accx[TMG], accy[TMG];
#pragma unroll
    for (int r = 0; r < TMG; ++r) { accx[r] = 0.0f; accy[r] = 0.0f; }

    const float* Ab = As + rg * TMG * KT;
    const float* Wc = W + col2;

    struct W4 { float2 w0, w1, w2, w3; };
    auto ldW = [&](int k) {
        W4 w;
        w.w0 = *(const float2*)(Wc + (size_t)(k + 0) * NT);
        w.w1 = *(const float2*)(Wc + (size_t)(k + 1) * NT);
        w.w2 = *(const float2*)(Wc + (size_t)(k + 2) * NT);
        w.w3 = *(const float2*)(Wc + (size_t)(k + 3) * NT);
        return w;
    };
    auto step = [&](int k, W4 w) {
#pragma unroll
        for (int r = 0; r < TMG; ++r) {
            float4 a = *(const float4*)(Ab + r * KT + k);
            accx[r] += a.x * w.w0.x + a.y * w.w1.x + a.z * w.w2.x + a.w * w.w3.x;
            accy[r] += a.x * w.w0.y + a.y * w.w1.y + a.z * w.w2.y + a.w * w.w3.y;
        }
    };

    // single-buffer rotation, NOT unrolled: one W chunk prefetched ahead.
    W4 wcur = ldW(0);
#pragma unroll 1
    for (int k = 0; k < KT - 4; k += 4) {
        W4 wnext = ldW(k + 4);
        step(k, wcur);
        wcur = wnext;
    }
    step(KT - 4, wcur);

    float bx = BIAS ? bias[col2] : 0.0f;
    float by = BIAS ? bias[col2 + 1] : 0.0f;
#pragma unroll
    for (int r = 0; r < TMG; ++r) {
        int gr = row0 + rg * TMG + r;
        if (gr < M) {
            float vx = accx[r], vy = accy[r];
            if (DIS_SCALE) { float dd = dis[gr]; vx *= dd; vy *= dd; }
            vx += bx; vy += by;
            if (RELU_OUT) { vx = fmaxf(vx, 0.0f); vy = fmaxf(vy, 0.0f); }
            *(float2*)(C + (size_t)gr * NT + col2) = make_float2(vx, vy);
        }
    }
}

// ================= CSR gather aggregation (validated round 5) =================
// out[d] = (maybe relu)( dis[d] * (y[d] + sum_{s in N(d)} y[s]) + bias )

template<bool RELU>
__global__ void gather128_kernel(const float* __restrict__ y, const int* __restrict__ row_start,
                                 const int* __restrict__ csr, const float* __restrict__ dis,
                                 const float* __restrict__ bias, float* __restrict__ out, int n) {
    int w = (blockIdx.x * blockDim.x + threadIdx.x) >> 6;
    if (w >= n) return;
    int lane = threadIdx.x & 63;

    float2 acc = ((const float2*)(y + (size_t)w * 128))[lane];  // self loop
    int p  = row_start[w];
    int pe = row_start[w + 1];
    for (; p + 1 < pe; p += 2) {
        int s0 = __builtin_amdgcn_readfirstlane(csr[p]);
        int s1 = __builtin_amdgcn_readfirstlane(csr[p + 1]);
        float2 v0 = ((const float2*)(y + (size_t)s0 * 128))[lane];
        float2 v1 = ((const float2*)(y + (size_t)s1 * 128))[lane];
        acc.x += v0.x + v1.x;
        acc.y += v0.y + v1.y;
    }
    if (p < pe) {
        int s0 = __builtin_amdgcn_readfirstlane(csr[p]);
        float2 v0 = ((const float2*)(y + (size_t)s0 * 128))[lane];
        acc.x += v0.x;
        acc.y += v0.y;
    }
    float dd = dis[w];
    float2 b = ((const float2*)bias)[lane];
    float ox = acc.x * dd + b.x;
    float oy = acc.y * dd + b.y;
    if (RELU) { ox = fmaxf(ox, 0.0f); oy = fmaxf(oy, 0.0f); }
    ((float2*)(out + (size_t)w * 128))[lane] = make_float2(ox, oy);
}

template<bool RELU>
__global__ void gather64_kernel(const float* __restrict__ y, const int* __restrict__ row_start,
                                const int* __restrict__ csr, const float* __restrict__ dis,
                                const float* __restrict__ bias, float* __restrict__ out, int n) {
    int w = (blockIdx.x * blockDim.x + threadIdx.x) >> 6;
    if (w >= n) return;
    int lane = threadIdx.x & 63;

    float acc = y[(size_t)w * 64 + lane];  // self loop
    int p  = row_start[w];
    int pe = row_start[w + 1];
    for (; p + 1 < pe; p += 2) {
        int s0 = __builtin_amdgcn_readfirstlane(csr[p]);
        int s1 = __builtin_amdgcn_readfirstlane(csr[p + 1]);
        float v0 = y[(size_t)s0 * 64 + lane];
        float v1 = y[(size_t)s1 * 64 + lane];
        acc += v0 + v1;
    }
    if (p < pe) {
        int s0 = __builtin_amdgcn_readfirstlane(csr[p]);
        acc += y[(size_t)s0 * 64 + lane];
    }
    float v = acc * dis[w] + bias[lane];
    if (RELU) v = fmaxf(v, 0.0f);
    out[(size_t)w * 64 + lane] = v;
}

// ================= launch =================

extern "C" void kernel_launch(void* const* d_in, const int* in_sizes, int n_in,
                              void* d_out, int out_size, void* d_ws, size_t ws_size,
                              hipStream_t stream) {
    const float* x     = (const float*)d_in[0];  // [n,180]
    const float* fc1_w = (const float*)d_in[1];  // [180,128]
    const float* fc1_b = (const float*)d_in[2];  // [128]
    const float* w1    = (const float*)d_in[3];  // [128,128]
    const float* b1    = (const float*)d_in[4];  // [128]
    const float* w2    = (const float*)d_in[5];  // [128,64]
    const float* b2    = (const float*)d_in[6];  // [64]
    const int*   edges = (const int*)d_in[7];    // [2,E] int32

    const int IN_DIM = 180, HID = 128, OUT_DIM = 64;
    const int n = in_sizes[0] / IN_DIM;          // 50000
    const int E = in_sizes[7] / 2;               // 800000
    const int* src = edges;
    const int* dst = edges + E;

    float* out = (float*)d_out;                  // [n,64]

    char* ws = (char*)d_ws;
    auto align = [](size_t v) { return (v + 255) & ~(size_t)255; };

    size_t off = 0;
    int*   deg       = (int*)(ws + off);  off += align((size_t)n * sizeof(int));
    float* dis       = (float*)(ws + off); off += align((size_t)n * sizeof(float));
    int*   row_start = (int*)(ws + off);  off += align((size_t)(n + 1) * sizeof(int));
    int*   cursor    = (int*)(ws + off);  off += align((size_t)n * sizeof(int));
    int*   bsum      = (int*)(ws + off);  off += align((size_t)256 * sizeof(int));
    int*   csr       = (int*)(ws + off);  off += align((size_t)E * sizeof(int));
    float* bufA      = (float*)(ws + off); off += align((size_t)n * HID * sizeof(float));
    float* bufB      = (float*)(ws + off); off += align((size_t)n * HID * sizeof(float));
    (void)ws_size;

    const int TM = 32;                            // rows per GEMM block (all shapes)
    const int nblk256 = (n + 255) / 256;
    const int eblk256 = (E + 255) / 256;
    const int ggrid = (n + TM - 1) / TM;          // 1563
    const int scan_blocks = (n + 1023) / 1024;    // 49 (<=256 required)

    // degree + normalization
    deg_init_kernel<<<nblk256, 256, 0, stream>>>(deg, n);
    deg_count_kernel<<<eblk256, 256, 0, stream>>>(dst, E, deg);
    dis_kernel<<<nblk256, 256, 0, stream>>>(deg, dis, n);

    // CSR build
    scan_partial_kernel<<<scan_blocks, 256, 0, stream>>>(deg, bsum, n);
    scan_bsum_kernel<<<1, 256, 0, stream>>>(bsum, scan_blocks);
    scan_fill_kernel<<<scan_blocks, 256, 0, stream>>>(deg, bsum, row_start, cursor, n, E);
    csr_fill_kernel<<<eblk256, 256, 0, stream>>>(src, dst, E, cursor, csr);

    // H1 = relu(x @ fc1_w + fc1_b) -> bufA      (64 col-threads, RG=4, TMG=8)
    gemm_kernel<180, 128, 8, 4, false, true, true, false>
        <<<ggrid, 256, TM * 180 * sizeof(float), stream>>>(
            x, fc1_w, fc1_b, nullptr, bufA, n);

    // y1 = dis * (H1 @ w1) -> bufB
    gemm_kernel<128, 128, 8, 4, false, false, false, true>
        <<<ggrid, 256, TM * 128 * sizeof(float), stream>>>(
            bufA, w1, nullptr, dis, bufB, n);

    // H2 = relu(dis[d]*(y1[d] + sum y1[s]) + b1) -> bufA
    gather128_kernel<true><<<(n + 3) / 4, 256, 0, stream>>>(
        bufB, row_start, csr, dis, b1, bufA, n);

    // y2 = dis * (H2 @ w2) -> bufB               (32 col-threads, RG=8, TMG=4)
    gemm_kernel<128, 64, 4, 8, false, false, false, true>
        <<<ggrid, 256, TM * 128 * sizeof(float), stream>>>(
            bufA, w2, nullptr, dis, bufB, n);

    // out = dis[d]*(y2[d] + sum y2[s]) + b2
    gather64_kernel<false><<<(n + 3) / 4, 256, 0, stream>>>(
        bufB, row_start, csr, dis, b2, out, n);
}